// Round 1
// baseline (1726.347 us; speedup 1.0000x reference)
//
#include <hip/hip_runtime.h>

#define NN 100000

// ---------- degree (in-degree on edges; +1 self-loop added in k_dinv) ----------
__global__ void k_deg(const int* __restrict__ dst, int E, float* __restrict__ deg) {
  int i = blockIdx.x * blockDim.x + threadIdx.x;
  if (i < E) atomicAdd(&deg[dst[i]], 1.0f);
}

__global__ void k_dinv(float* __restrict__ deg, int n) {
  int i = blockIdx.x * blockDim.x + threadIdx.x;
  if (i < n) deg[i] = rsqrtf(deg[i] + 1.0f);  // deg>=1 always (self-loop)
}

// ---------- hA = x @ W1 : [N,128] x [128,128] ----------
// block: 256 threads, tile 64 rows x 128 cols, k-blocked by 16.
__global__ __launch_bounds__(256) void k_gemm1(const float* __restrict__ x,
                                               const float* __restrict__ W,
                                               float* __restrict__ out, int N) {
  __shared__ float xs[16][68];    // [k][row], pad 68 (stride 272B, 16B-aligned rows)
  __shared__ float wsb[16][128];  // [k][col]
  const int row0 = blockIdx.x * 64;
  const int t = threadIdx.x;
  const int tx = t & 31;   // col/4
  const int ty = t >> 5;   // row-group (8 rows each)
  const int lr = t >> 2;           // 0..63 row for x staging
  const int lc = (t & 3) << 2;     // k offset 0,4,8,12
  const int wr = t >> 5;           // 0..7
  const int wc = (t & 31) << 2;
  float acc[8][4] = {};

  for (int k0 = 0; k0 < 128; k0 += 16) {
    float4 xv = make_float4(0.f, 0.f, 0.f, 0.f);
    int row = row0 + lr;
    if (row < N) xv = *(const float4*)&x[row * 128 + k0 + lc];
    xs[lc + 0][lr] = xv.x; xs[lc + 1][lr] = xv.y;
    xs[lc + 2][lr] = xv.z; xs[lc + 3][lr] = xv.w;
    *(float4*)&wsb[wr][wc]     = *(const float4*)&W[(k0 + wr) * 128 + wc];
    *(float4*)&wsb[wr + 8][wc] = *(const float4*)&W[(k0 + wr + 8) * 128 + wc];
    __syncthreads();
#pragma unroll
    for (int kk = 0; kk < 16; ++kk) {
      float4 wv = *(const float4*)&wsb[kk][tx * 4];
      float4 xa = *(const float4*)&xs[kk][ty * 8];
      float4 xb = *(const float4*)&xs[kk][ty * 8 + 4];
      float xr[8] = {xa.x, xa.y, xa.z, xa.w, xb.x, xb.y, xb.z, xb.w};
#pragma unroll
      for (int i = 0; i < 8; ++i) {
        acc[i][0] += xr[i] * wv.x; acc[i][1] += xr[i] * wv.y;
        acc[i][2] += xr[i] * wv.z; acc[i][3] += xr[i] * wv.w;
      }
    }
    __syncthreads();
  }
#pragma unroll
  for (int i = 0; i < 8; ++i) {
    int row = row0 + ty * 8 + i;
    if (row < N)
      *(float4*)&out[row * 128 + tx * 4] =
          make_float4(acc[i][0], acc[i][1], acc[i][2], acc[i][3]);
  }
}

// ---------- layer-1 edge propagation: acc[d] += hA[s] * dinv[s]*dinv[d] ----------
// one wave (64 lanes) per edge; 2 floats/lane
__global__ __launch_bounds__(256) void k_prop1(const int* __restrict__ src,
                                               const int* __restrict__ dst, int E,
                                               const float* __restrict__ dinv,
                                               const float* __restrict__ hA,
                                               float* __restrict__ acc) {
  int e = blockIdx.x * 4 + (threadIdx.x >> 6);
  if (e >= E) return;
  int lane = threadIdx.x & 63;
  int s = src[e], d = dst[e];
  float w = dinv[s] * dinv[d];
  float2 v = *(const float2*)&hA[(size_t)s * 128 + lane * 2];
  float* p = &acc[(size_t)d * 128 + lane * 2];
  atomicAdd(p, v.x * w);
  atomicAdd(p + 1, v.y * w);
}

// ---------- fused: relu(acc + hA*dinv^2 + b1) @ W2 -> t2base[N,2] ----------
__global__ __launch_bounds__(128) void k_layer2in(const float* __restrict__ hA,
                                                  const float* __restrict__ acc,
                                                  const float* __restrict__ dinv,
                                                  const float* __restrict__ b1,
                                                  const float* __restrict__ W2,
                                                  float* __restrict__ t2base, int N) {
  int i = blockIdx.x;
  int f = threadIdx.x;  // 0..127
  float di = dinv[i];
  float v = acc[(size_t)i * 128 + f] + hA[(size_t)i * 128 + f] * di * di + b1[f];
  v = fmaxf(v, 0.0f);
  float p0 = v * W2[f * 2 + 0];
  float p1 = v * W2[f * 2 + 1];
#pragma unroll
  for (int off = 32; off > 0; off >>= 1) {
    p0 += __shfl_down(p0, off);
    p1 += __shfl_down(p1, off);
  }
  __shared__ float red[2][2];
  int w = threadIdx.x >> 6;
  if ((threadIdx.x & 63) == 0) { red[w][0] = p0; red[w][1] = p1; }
  __syncthreads();
  if (threadIdx.x == 0) {
    float2 r = make_float2(red[0][0] + red[1][0], red[0][1] + red[1][1]);
    *(float2*)&t2base[i * 2] = r;
  }
}

// ---------- layer-2 edge propagation (2 floats/edge) ----------
__global__ void k_prop2(const int* __restrict__ src, const int* __restrict__ dst, int E,
                        const float* __restrict__ dinv, const float* __restrict__ t2base,
                        float* __restrict__ t2acc) {
  int e = blockIdx.x * blockDim.x + threadIdx.x;
  if (e >= E) return;
  int s = src[e], d = dst[e];
  float w = dinv[s] * dinv[d];
  float2 v = *(const float2*)&t2base[s * 2];
  atomicAdd(&t2acc[d * 2], v.x * w);
  atomicAdd(&t2acc[d * 2 + 1], v.y * w);
}

// ---------- final: out = t2acc + t2base*dinv^2 + b2 + x@W_skip + b_skip ----------
// one wave per node for the 128-dot skip GEMM
__global__ __launch_bounds__(256) void k_final(const float* __restrict__ x,
                                               const float* __restrict__ W_skip,
                                               const float* __restrict__ b_skip,
                                               const float* __restrict__ b2,
                                               const float* __restrict__ t2base,
                                               const float* __restrict__ t2acc,
                                               const float* __restrict__ dinv,
                                               float* __restrict__ out, int N) {
  int i = blockIdx.x * 4 + (threadIdx.x >> 6);
  if (i >= N) return;
  int lane = threadIdx.x & 63;
  float2 xv = *(const float2*)&x[(size_t)i * 128 + lane * 2];
  float4 wv = *(const float4*)&W_skip[lane * 4];  // rows 2*lane, 2*lane+1
  float a0 = xv.x * wv.x + xv.y * wv.z;
  float a1 = xv.x * wv.y + xv.y * wv.w;
#pragma unroll
  for (int off = 32; off > 0; off >>= 1) {
    a0 += __shfl_down(a0, off);
    a1 += __shfl_down(a1, off);
  }
  if (lane == 0) {
    float di = dinv[i], d2 = di * di;
    float o0 = t2acc[i * 2 + 0] + t2base[i * 2 + 0] * d2 + b2[0] + a0 + b_skip[0];
    float o1 = t2acc[i * 2 + 1] + t2base[i * 2 + 1] * d2 + b2[1] + a1 + b_skip[1];
    *(float2*)&out[i * 2] = make_float2(o0, o1);
  }
}

extern "C" void kernel_launch(void* const* d_in, const int* in_sizes, int n_in,
                              void* d_out, int out_size, void* d_ws, size_t ws_size,
                              hipStream_t stream) {
  const float* x      = (const float*)d_in[0];
  const int*   edges  = (const int*)d_in[1];
  const float* W1     = (const float*)d_in[2];
  const float* b1     = (const float*)d_in[3];
  const float* W2     = (const float*)d_in[4];
  const float* b2     = (const float*)d_in[5];
  const float* W_skip = (const float*)d_in[6];
  const float* b_skip = (const float*)d_in[7];
  float* out = (float*)d_out;

  const int N = NN;
  const int E = in_sizes[1] / 2;
  const int* src = edges;
  const int* dst = edges + E;

  // workspace layout (floats): [deg N][t2acc 2N][h1acc 128N] | [t2base 2N][hA 128N]
  float* deg    = (float*)d_ws;
  float* t2acc  = deg + N;
  float* h1acc  = t2acc + 2 * (size_t)N;
  float* t2base = h1acc + 128 * (size_t)N;
  float* hA     = t2base + 2 * (size_t)N;

  // zero deg + t2acc + h1acc (contiguous prefix: 131*N floats)
  hipMemsetAsync(d_ws, 0, (size_t)131 * N * sizeof(float), stream);

  k_deg<<<(E + 255) / 256, 256, 0, stream>>>(dst, E, deg);
  k_dinv<<<(N + 255) / 256, 256, 0, stream>>>(deg, N);
  k_gemm1<<<(N + 63) / 64, 256, 0, stream>>>(x, W1, hA, N);
  k_prop1<<<(E + 3) / 4, 256, 0, stream>>>(src, dst, E, deg, hA, h1acc);
  k_layer2in<<<N, 128, 0, stream>>>(hA, h1acc, deg, b1, W2, t2base, N);
  k_prop2<<<(E + 255) / 256, 256, 0, stream>>>(src, dst, E, deg, t2base, t2acc);
  k_final<<<(N + 3) / 4, 256, 0, stream>>>(x, W_skip, b_skip, b2, t2base, t2acc, deg,
                                           out, N);
}

// Round 2
// 637.570 us; speedup vs baseline: 2.7077x; 2.7077x over previous
//
#include <hip/hip_runtime.h>

#define NN 100000

// ---------- degree count (int) ----------
__global__ void k_deg(const int* __restrict__ dst, int E, int* __restrict__ cnt) {
  int i = blockIdx.x * blockDim.x + threadIdx.x;
  if (i < E) atomicAdd(&cnt[dst[i]], 1);
}

__global__ void k_dinv(const int* __restrict__ cnt, float* __restrict__ dinv, int n) {
  int i = blockIdx.x * blockDim.x + threadIdx.x;
  if (i < n) dinv[i] = rsqrtf((float)cnt[i] + 1.0f);  // +1 self-loop
}

// ---------- single-block exclusive scan of cnt -> ofs[0..n] ----------
__global__ __launch_bounds__(1024) void k_scan(const int* __restrict__ cnt,
                                               int* __restrict__ ofs, int n) {
  __shared__ int part[1024];
  const int t = threadIdx.x;
  const int per = (n + 1023) / 1024;
  const int beg = t * per;
  const int end = min(beg + per, n);
  int s = 0;
  for (int i = beg; i < end; ++i) s += cnt[i];
  part[t] = s;
  __syncthreads();
  for (int off = 1; off < 1024; off <<= 1) {
    int v = (t >= off) ? part[t - off] : 0;
    __syncthreads();
    part[t] += v;
    __syncthreads();
  }
  int ex = (t == 0) ? 0 : part[t - 1];
  for (int i = beg; i < end; ++i) { ofs[i] = ex; ex += cnt[i]; }
  if (t == 1023) ofs[n] = ex;
}

// ---------- fill CSR bins: bin[ofs[d] + pos] = src ----------
__global__ void k_binfill(const int* __restrict__ src, const int* __restrict__ dst,
                          int E, const int* __restrict__ ofs, int* __restrict__ cursor,
                          int* __restrict__ bin) {
  int e = blockIdx.x * blockDim.x + threadIdx.x;
  if (e >= E) return;
  int d = dst[e];
  int pos = atomicAdd(&cursor[d], 1);
  bin[ofs[d] + pos] = src[e];
}

// ---------- hA = x @ W1 : [N,128] x [128,128] ----------
__global__ __launch_bounds__(256) void k_gemm1(const float* __restrict__ x,
                                               const float* __restrict__ W,
                                               float* __restrict__ out, int N) {
  __shared__ float xs[16][68];
  __shared__ float wsb[16][128];
  const int row0 = blockIdx.x * 64;
  const int t = threadIdx.x;
  const int tx = t & 31;
  const int ty = t >> 5;
  const int lr = t >> 2;
  const int lc = (t & 3) << 2;
  const int wr = t >> 5;
  const int wc = (t & 31) << 2;
  float acc[8][4] = {};

  for (int k0 = 0; k0 < 128; k0 += 16) {
    float4 xv = make_float4(0.f, 0.f, 0.f, 0.f);
    int row = row0 + lr;
    if (row < N) xv = *(const float4*)&x[row * 128 + k0 + lc];
    xs[lc + 0][lr] = xv.x; xs[lc + 1][lr] = xv.y;
    xs[lc + 2][lr] = xv.z; xs[lc + 3][lr] = xv.w;
    *(float4*)&wsb[wr][wc]     = *(const float4*)&W[(k0 + wr) * 128 + wc];
    *(float4*)&wsb[wr + 8][wc] = *(const float4*)&W[(k0 + wr + 8) * 128 + wc];
    __syncthreads();
#pragma unroll
    for (int kk = 0; kk < 16; ++kk) {
      float4 wv = *(const float4*)&wsb[kk][tx * 4];
      float4 xa = *(const float4*)&xs[kk][ty * 8];
      float4 xb = *(const float4*)&xs[kk][ty * 8 + 4];
      float xr[8] = {xa.x, xa.y, xa.z, xa.w, xb.x, xb.y, xb.z, xb.w};
#pragma unroll
      for (int i = 0; i < 8; ++i) {
        acc[i][0] += xr[i] * wv.x; acc[i][1] += xr[i] * wv.y;
        acc[i][2] += xr[i] * wv.z; acc[i][3] += xr[i] * wv.w;
      }
    }
    __syncthreads();
  }
#pragma unroll
  for (int i = 0; i < 8; ++i) {
    int row = row0 + ty * 8 + i;
    if (row < N)
      *(float4*)&out[row * 128 + tx * 4] =
          make_float4(acc[i][0], acc[i][1], acc[i][2], acc[i][3]);
  }
}

// ---------- fused layer-1: CSR gather + self-loop + bias + relu + @W2 ----------
// one wave per destination node; 2 floats/lane
__global__ __launch_bounds__(256) void k_gather1(const int* __restrict__ ofs,
                                                 const int* __restrict__ bin,
                                                 const float* __restrict__ dinv,
                                                 const float* __restrict__ hA,
                                                 const float* __restrict__ b1,
                                                 const float* __restrict__ W2,
                                                 float* __restrict__ t2base, int N) {
  int d = blockIdx.x * 4 + (threadIdx.x >> 6);
  if (d >= N) return;
  const int lane = threadIdx.x & 63;
  const int beg = ofs[d], end = ofs[d + 1];
  float ax = 0.f, ay = 0.f;
  int e = beg;
  for (; e + 1 < end; e += 2) {   // 2-deep pipeline for MLP
    int s0 = bin[e], s1 = bin[e + 1];
    float w0 = dinv[s0], w1 = dinv[s1];
    float2 v0 = *(const float2*)&hA[(size_t)s0 * 128 + lane * 2];
    float2 v1 = *(const float2*)&hA[(size_t)s1 * 128 + lane * 2];
    ax += w0 * v0.x + w1 * v1.x;
    ay += w0 * v0.y + w1 * v1.y;
  }
  if (e < end) {
    int s = bin[e];
    float w = dinv[s];
    float2 v = *(const float2*)&hA[(size_t)s * 128 + lane * 2];
    ax += w * v.x; ay += w * v.y;
  }
  const float dd = dinv[d];
  float2 hs = *(const float2*)&hA[(size_t)d * 128 + lane * 2];
  float v0 = ax * dd + hs.x * dd * dd + b1[lane * 2];
  float v1 = ay * dd + hs.y * dd * dd + b1[lane * 2 + 1];
  v0 = fmaxf(v0, 0.f);
  v1 = fmaxf(v1, 0.f);
  float4 w2 = *(const float4*)&W2[lane * 4];  // rows 2*lane, 2*lane+1 of [128,2]
  float p0 = v0 * w2.x + v1 * w2.z;
  float p1 = v0 * w2.y + v1 * w2.w;
#pragma unroll
  for (int off = 32; off > 0; off >>= 1) {
    p0 += __shfl_down(p0, off);
    p1 += __shfl_down(p1, off);
  }
  if (lane == 0) *(float2*)&t2base[d * 2] = make_float2(p0, p1);
}

// ---------- fused final: layer-2 CSR gather + self-loop + b2 + x@W_skip + b_skip ----
// one wave per node; skip dot over lanes, edge gather strided over lanes
__global__ __launch_bounds__(256) void k_final(const float* __restrict__ x,
                                               const float* __restrict__ W_skip,
                                               const float* __restrict__ b_skip,
                                               const float* __restrict__ b2,
                                               const float* __restrict__ t2base,
                                               const float* __restrict__ dinv,
                                               const int* __restrict__ ofs,
                                               const int* __restrict__ bin,
                                               float* __restrict__ out, int N) {
  int i = blockIdx.x * 4 + (threadIdx.x >> 6);
  if (i >= N) return;
  const int lane = threadIdx.x & 63;
  // skip GEMM partials
  float2 xv = *(const float2*)&x[(size_t)i * 128 + lane * 2];
  float4 wv = *(const float4*)&W_skip[lane * 4];
  float a0 = xv.x * wv.x + xv.y * wv.z;
  float a1 = xv.x * wv.y + xv.y * wv.w;
  // layer-2 gather partials (lanes stride the edge list)
  const int beg = ofs[i], end = ofs[i + 1];
  float g0 = 0.f, g1 = 0.f;
  for (int e = beg + lane; e < end; e += 64) {
    int s = bin[e];
    float w = dinv[s];
    float2 t = *(const float2*)&t2base[s * 2];
    g0 += w * t.x; g1 += w * t.y;
  }
#pragma unroll
  for (int off = 32; off > 0; off >>= 1) {
    a0 += __shfl_down(a0, off);
    a1 += __shfl_down(a1, off);
    g0 += __shfl_down(g0, off);
    g1 += __shfl_down(g1, off);
  }
  if (lane == 0) {
    float di = dinv[i], d2 = di * di;
    float2 ts = *(const float2*)&t2base[i * 2];
    float o0 = g0 * di + ts.x * d2 + b2[0] + a0 + b_skip[0];
    float o1 = g1 * di + ts.y * d2 + b2[1] + a1 + b_skip[1];
    *(float2*)&out[i * 2] = make_float2(o0, o1);
  }
}

extern "C" void kernel_launch(void* const* d_in, const int* in_sizes, int n_in,
                              void* d_out, int out_size, void* d_ws, size_t ws_size,
                              hipStream_t stream) {
  const float* x      = (const float*)d_in[0];
  const int*   edges  = (const int*)d_in[1];
  const float* W1     = (const float*)d_in[2];
  const float* b1     = (const float*)d_in[3];
  const float* W2     = (const float*)d_in[4];
  const float* b2     = (const float*)d_in[5];
  const float* W_skip = (const float*)d_in[6];
  const float* b_skip = (const float*)d_in[7];
  float* out = (float*)d_out;

  const int N = NN;
  const int E = in_sizes[1] / 2;
  const int* src = edges;
  const int* dst = edges + E;

  // workspace: [cnt N][cursor N][ofs N+4][dinv N][bin E][t2base 2N][hA 128N]
  int*   cnt    = (int*)d_ws;
  int*   cursor = cnt + N;
  int*   ofs    = cursor + N;
  float* dinv   = (float*)(ofs + N + 4);
  int*   bin    = (int*)(dinv + N);
  float* t2base = (float*)(bin + E);
  float* hA     = t2base + 2 * (size_t)N;

  hipMemsetAsync(cnt, 0, 2 * (size_t)N * sizeof(int), stream);  // cnt + cursor

  k_deg<<<(E + 255) / 256, 256, 0, stream>>>(dst, E, cnt);
  k_dinv<<<(N + 255) / 256, 256, 0, stream>>>(cnt, dinv, N);
  k_scan<<<1, 1024, 0, stream>>>(cnt, ofs, N);
  k_binfill<<<(E + 255) / 256, 256, 0, stream>>>(src, dst, E, ofs, cursor, bin);
  k_gemm1<<<(N + 63) / 64, 256, 0, stream>>>(x, W1, hA, N);
  k_gather1<<<(N + 3) / 4, 256, 0, stream>>>(ofs, bin, dinv, hA, b1, W2, t2base, N);
  k_final<<<(N + 3) / 4, 256, 0, stream>>>(x, W_skip, b_skip, b2, t2base, dinv, ofs,
                                           bin, out, N);
}

// Round 3
// 486.124 us; speedup vs baseline: 3.5512x; 1.3115x over previous
//
#include <hip/hip_runtime.h>

#define NN 100000

// ---------- degree count (int) ----------
__global__ void k_deg(const int* __restrict__ dst, int E, int* __restrict__ cnt) {
  int i = blockIdx.x * blockDim.x + threadIdx.x;
  if (i < E) atomicAdd(&cnt[dst[i]], 1);
}

// ---------- parallel segment allocator + dinv (replaces ordered scan) ----------
// CSR segment order is irrelevant (bin fill is atomic-ordered anyway), so each
// block reserves space with ONE atomicAdd instead of a serial prefix sum.
__global__ __launch_bounds__(256) void k_alloc(const int* __restrict__ cnt,
                                               int* __restrict__ ofs,
                                               float* __restrict__ dinv,
                                               int* __restrict__ total, int n) {
  int i = blockIdx.x * blockDim.x + threadIdx.x;
  int c = (i < n) ? cnt[i] : 0;
  if (i < n) dinv[i] = rsqrtf((float)c + 1.0f);  // +1 self-loop
  const int lane = threadIdx.x & 63;
  const int wid = threadIdx.x >> 6;
  int incl = c;
#pragma unroll
  for (int off = 1; off < 64; off <<= 1) {
    int v = __shfl_up(incl, off);
    if (lane >= off) incl += v;
  }
  __shared__ int wsum[4];
  __shared__ int base;
  if (lane == 63) wsum[wid] = incl;
  __syncthreads();
  if (threadIdx.x == 0) {
    int s0 = wsum[0], s1 = wsum[1], s2 = wsum[2], s3 = wsum[3];
    base = atomicAdd(total, s0 + s1 + s2 + s3);
    wsum[0] = 0; wsum[1] = s0; wsum[2] = s0 + s1; wsum[3] = s0 + s1 + s2;
  }
  __syncthreads();
  if (i < n) ofs[i] = base + wsum[wid] + incl - c;
}

// ---------- fill CSR bins: bin[ofs[d] + pos] = src ----------
__global__ void k_binfill(const int* __restrict__ src, const int* __restrict__ dst,
                          int E, const int* __restrict__ ofs, int* __restrict__ cursor,
                          int* __restrict__ bin) {
  int e = blockIdx.x * blockDim.x + threadIdx.x;
  if (e >= E) return;
  int d = dst[e];
  int pos = atomicAdd(&cursor[d], 1);
  bin[ofs[d] + pos] = src[e];
}

// ---------- hA = x @ W1 : [N,128] x [128,128] ----------
__global__ __launch_bounds__(256) void k_gemm1(const float* __restrict__ x,
                                               const float* __restrict__ W,
                                               float* __restrict__ out, int N) {
  __shared__ float xs[16][68];
  __shared__ float wsb[16][128];
  const int row0 = blockIdx.x * 64;
  const int t = threadIdx.x;
  const int tx = t & 31;
  const int ty = t >> 5;
  const int lr = t >> 2;
  const int lc = (t & 3) << 2;
  const int wr = t >> 5;
  const int wc = (t & 31) << 2;
  float acc[8][4] = {};

  for (int k0 = 0; k0 < 128; k0 += 16) {
    float4 xv = make_float4(0.f, 0.f, 0.f, 0.f);
    int row = row0 + lr;
    if (row < N) xv = *(const float4*)&x[row * 128 + k0 + lc];
    xs[lc + 0][lr] = xv.x; xs[lc + 1][lr] = xv.y;
    xs[lc + 2][lr] = xv.z; xs[lc + 3][lr] = xv.w;
    *(float4*)&wsb[wr][wc]     = *(const float4*)&W[(k0 + wr) * 128 + wc];
    *(float4*)&wsb[wr + 8][wc] = *(const float4*)&W[(k0 + wr + 8) * 128 + wc];
    __syncthreads();
#pragma unroll
    for (int kk = 0; kk < 16; ++kk) {
      float4 wv = *(const float4*)&wsb[kk][tx * 4];
      float4 xa = *(const float4*)&xs[kk][ty * 8];
      float4 xb = *(const float4*)&xs[kk][ty * 8 + 4];
      float xr[8] = {xa.x, xa.y, xa.z, xa.w, xb.x, xb.y, xb.z, xb.w};
#pragma unroll
      for (int i = 0; i < 8; ++i) {
        acc[i][0] += xr[i] * wv.x; acc[i][1] += xr[i] * wv.y;
        acc[i][2] += xr[i] * wv.z; acc[i][3] += xr[i] * wv.w;
      }
    }
    __syncthreads();
  }
#pragma unroll
  for (int i = 0; i < 8; ++i) {
    int row = row0 + ty * 8 + i;
    if (row < N)
      *(float4*)&out[row * 128 + tx * 4] =
          make_float4(acc[i][0], acc[i][1], acc[i][2], acc[i][3]);
  }
}

// ---------- fused layer-1: CSR gather + self-loop + bias + relu + @W2 ----------
// one wave per destination node; 2 floats/lane
__global__ __launch_bounds__(256) void k_gather1(const int* __restrict__ ofs,
                                                 const int* __restrict__ cnt,
                                                 const int* __restrict__ bin,
                                                 const float* __restrict__ dinv,
                                                 const float* __restrict__ hA,
                                                 const float* __restrict__ b1,
                                                 const float* __restrict__ W2,
                                                 float* __restrict__ t2base, int N) {
  int d = blockIdx.x * 4 + (threadIdx.x >> 6);
  if (d >= N) return;
  const int lane = threadIdx.x & 63;
  const int beg = ofs[d], end = beg + cnt[d];
  float ax = 0.f, ay = 0.f;
  int e = beg;
  for (; e + 1 < end; e += 2) {
    int s0 = bin[e], s1 = bin[e + 1];
    float w0 = dinv[s0], w1 = dinv[s1];
    float2 v0 = *(const float2*)&hA[(size_t)s0 * 128 + lane * 2];
    float2 v1 = *(const float2*)&hA[(size_t)s1 * 128 + lane * 2];
    ax += w0 * v0.x + w1 * v1.x;
    ay += w0 * v0.y + w1 * v1.y;
  }
  if (e < end) {
    int s = bin[e];
    float w = dinv[s];
    float2 v = *(const float2*)&hA[(size_t)s * 128 + lane * 2];
    ax += w * v.x; ay += w * v.y;
  }
  const float dd = dinv[d];
  float2 hs = *(const float2*)&hA[(size_t)d * 128 + lane * 2];
  float v0 = ax * dd + hs.x * dd * dd + b1[lane * 2];
  float v1 = ay * dd + hs.y * dd * dd + b1[lane * 2 + 1];
  v0 = fmaxf(v0, 0.f);
  v1 = fmaxf(v1, 0.f);
  float4 w2 = *(const float4*)&W2[lane * 4];
  float p0 = v0 * w2.x + v1 * w2.z;
  float p1 = v0 * w2.y + v1 * w2.w;
#pragma unroll
  for (int off = 32; off > 0; off >>= 1) {
    p0 += __shfl_down(p0, off);
    p1 += __shfl_down(p1, off);
  }
  if (lane == 0) *(float2*)&t2base[d * 2] = make_float2(p0, p1);
}

// ---------- fused final: layer-2 CSR gather + self-loop + b2 + x@W_skip + b_skip ----
__global__ __launch_bounds__(256) void k_final(const float* __restrict__ x,
                                               const float* __restrict__ W_skip,
                                               const float* __restrict__ b_skip,
                                               const float* __restrict__ b2,
                                               const float* __restrict__ t2base,
                                               const float* __restrict__ dinv,
                                               const int* __restrict__ ofs,
                                               const int* __restrict__ cnt,
                                               const int* __restrict__ bin,
                                               float* __restrict__ out, int N) {
  int i = blockIdx.x * 4 + (threadIdx.x >> 6);
  if (i >= N) return;
  const int lane = threadIdx.x & 63;
  float2 xv = *(const float2*)&x[(size_t)i * 128 + lane * 2];
  float4 wv = *(const float4*)&W_skip[lane * 4];
  float a0 = xv.x * wv.x + xv.y * wv.z;
  float a1 = xv.x * wv.y + xv.y * wv.w;
  const int beg = ofs[i], end = beg + cnt[i];
  float g0 = 0.f, g1 = 0.f;
  for (int e = beg + lane; e < end; e += 64) {
    int s = bin[e];
    float w = dinv[s];
    float2 t = *(const float2*)&t2base[s * 2];
    g0 += w * t.x; g1 += w * t.y;
  }
#pragma unroll
  for (int off = 32; off > 0; off >>= 1) {
    a0 += __shfl_down(a0, off);
    a1 += __shfl_down(a1, off);
    g0 += __shfl_down(g0, off);
    g1 += __shfl_down(g1, off);
  }
  if (lane == 0) {
    float di = dinv[i], d2 = di * di;
    float2 ts = *(const float2*)&t2base[i * 2];
    float o0 = g0 * di + ts.x * d2 + b2[0] + a0 + b_skip[0];
    float o1 = g1 * di + ts.y * d2 + b2[1] + a1 + b_skip[1];
    *(float2*)&out[i * 2] = make_float2(o0, o1);
  }
}

extern "C" void kernel_launch(void* const* d_in, const int* in_sizes, int n_in,
                              void* d_out, int out_size, void* d_ws, size_t ws_size,
                              hipStream_t stream) {
  const float* x      = (const float*)d_in[0];
  const int*   edges  = (const int*)d_in[1];
  const float* W1     = (const float*)d_in[2];
  const float* b1     = (const float*)d_in[3];
  const float* W2     = (const float*)d_in[4];
  const float* b2     = (const float*)d_in[5];
  const float* W_skip = (const float*)d_in[6];
  const float* b_skip = (const float*)d_in[7];
  float* out = (float*)d_out;

  const int N = NN;
  const int E = in_sizes[1] / 2;
  const int* src = edges;
  const int* dst = edges + E;

  // workspace: [cnt N][cursor N][total 4][ofs N+4][dinv N][bin E][t2base 2N][hA 128N]
  int*   cnt    = (int*)d_ws;
  int*   cursor = cnt + N;
  int*   total  = cursor + N;
  int*   ofs    = total + 4;
  float* dinv   = (float*)(ofs + N + 4);
  int*   bin    = (int*)(dinv + N);
  float* t2base = (float*)(bin + E);
  float* hA     = t2base + 2 * (size_t)N;

  hipMemsetAsync(cnt, 0, (2 * (size_t)N + 4) * sizeof(int), stream);  // cnt+cursor+total

  k_deg<<<(E + 255) / 256, 256, 0, stream>>>(dst, E, cnt);
  k_alloc<<<(N + 255) / 256, 256, 0, stream>>>(cnt, ofs, dinv, total, N);
  k_binfill<<<(E + 255) / 256, 256, 0, stream>>>(src, dst, E, ofs, cursor, bin);
  k_gemm1<<<(N + 63) / 64, 256, 0, stream>>>(x, W1, hA, N);
  k_gather1<<<(N + 3) / 4, 256, 0, stream>>>(ofs, cnt, bin, dinv, hA, b1, W2, t2base, N);
  k_final<<<(N + 3) / 4, 256, 0, stream>>>(x, W_skip, b_skip, b2, t2base, dinv, ofs,
                                           cnt, bin, out, N);
}

// Round 4
// 394.286 us; speedup vs baseline: 4.3784x; 1.2329x over previous
//
#include <hip/hip_runtime.h>

#define NN 100000

typedef __attribute__((ext_vector_type(8))) short short8;
typedef __attribute__((ext_vector_type(4))) float f32x4;

__device__ __forceinline__ unsigned short f2bf(float f) {
  union { float f; unsigned int u; } v;
  v.f = f;
  unsigned int r = (v.u + 0x7fffu + ((v.u >> 16) & 1u)) >> 16;  // RNE
  return (unsigned short)r;
}
__device__ __forceinline__ float bf2f(unsigned short u) {
  union { unsigned int u; float f; } v;
  v.u = ((unsigned int)u) << 16;
  return v.f;
}

// ---------- degree count (int) ----------
__global__ void k_deg(const int* __restrict__ dst, int E, int* __restrict__ cnt) {
  int i = blockIdx.x * blockDim.x + threadIdx.x;
  if (i < E) atomicAdd(&cnt[dst[i]], 1);
}

// ---------- parallel segment allocator + dinv ----------
__global__ __launch_bounds__(256) void k_alloc(const int* __restrict__ cnt,
                                               int* __restrict__ ofs,
                                               float* __restrict__ dinv,
                                               int* __restrict__ total, int n) {
  int i = blockIdx.x * blockDim.x + threadIdx.x;
  int c = (i < n) ? cnt[i] : 0;
  if (i < n) dinv[i] = rsqrtf((float)c + 1.0f);  // +1 self-loop
  const int lane = threadIdx.x & 63;
  const int wid = threadIdx.x >> 6;
  int incl = c;
#pragma unroll
  for (int off = 1; off < 64; off <<= 1) {
    int v = __shfl_up(incl, off);
    if (lane >= off) incl += v;
  }
  __shared__ int wsum[4];
  __shared__ int base;
  if (lane == 63) wsum[wid] = incl;
  __syncthreads();
  if (threadIdx.x == 0) {
    int s0 = wsum[0], s1 = wsum[1], s2 = wsum[2], s3 = wsum[3];
    base = atomicAdd(total, s0 + s1 + s2 + s3);
    wsum[0] = 0; wsum[1] = s0; wsum[2] = s0 + s1; wsum[3] = s0 + s1 + s2;
  }
  __syncthreads();
  if (i < n) ofs[i] = base + wsum[wid] + incl - c;
}

// ---------- fill CSR bins ----------
__global__ void k_binfill(const int* __restrict__ src, const int* __restrict__ dst,
                          int E, const int* __restrict__ ofs, int* __restrict__ cursor,
                          int* __restrict__ bin) {
  int e = blockIdx.x * blockDim.x + threadIdx.x;
  if (e >= E) return;
  int d = dst[e];
  int pos = atomicAdd(&cursor[d], 1);
  bin[ofs[d] + pos] = src[e];
}

// ---------- W1 [128,128] fp32 -> Btg [n][k] bf16 (transposed) ----------
__global__ void k_wprep(const float* __restrict__ W1, unsigned short* __restrict__ Btg) {
  int e = blockIdx.x * blockDim.x + threadIdx.x;  // 0..16383
  int n = e >> 7, k = e & 127;
  Btg[e] = f2bf(W1[k * 128 + n]);
}

// ---------- hA16 = bf16(x @ W1) via MFMA 16x16x32 ----------
// block: 256 threads = 4 waves, tile 64 rows x 128 cols. B (W1^T bf16) in LDS,
// A fragments loaded straight from global x (rows are wave-private).
__global__ __launch_bounds__(256) void k_gemm1(const float* __restrict__ x,
                                               const unsigned short* __restrict__ Btg,
                                               unsigned short* __restrict__ hA16,
                                               int N) {
  __shared__ __align__(16) unsigned short Bs[128][136];  // [n][k], pad to 272B rows
  const int t = threadIdx.x;
#pragma unroll
  for (int it = 0; it < 8; ++it) {
    int idx = t + it * 256;          // 2048 chunks of 8 shorts
    int n = idx >> 4, c = (idx & 15) * 8;
    *(uint4*)&Bs[n][c] = *(const uint4*)&Btg[n * 128 + c];
  }
  __syncthreads();

  const int lane = t & 63, w = t >> 6;
  const int m = lane & 15, q = lane >> 4;
  const int grow = blockIdx.x * 64 + w * 16 + m;     // A row for this lane
  const bool valid = grow < N;
  const float* xp = &x[(size_t)(valid ? grow : 0) * 128];

  f32x4 acc[8];
#pragma unroll
  for (int nt = 0; nt < 8; ++nt) acc[nt] = (f32x4){0.f, 0.f, 0.f, 0.f};

#pragma unroll
  for (int ks = 0; ks < 4; ++ks) {
    short8 a;
    if (valid) {
      const float* p = xp + ks * 32 + q * 8;
      float4 f0 = *(const float4*)p;
      float4 f1 = *(const float4*)(p + 4);
      a[0] = (short)f2bf(f0.x); a[1] = (short)f2bf(f0.y);
      a[2] = (short)f2bf(f0.z); a[3] = (short)f2bf(f0.w);
      a[4] = (short)f2bf(f1.x); a[5] = (short)f2bf(f1.y);
      a[6] = (short)f2bf(f1.z); a[7] = (short)f2bf(f1.w);
    } else {
      a = (short8)0;
    }
#pragma unroll
    for (int nt = 0; nt < 8; ++nt) {
      short8 b = *(const short8*)&Bs[nt * 16 + m][ks * 32 + q * 8];
      acc[nt] = __builtin_amdgcn_mfma_f32_16x16x32_bf16(a, b, acc[nt], 0, 0, 0);
    }
  }

  // C/D layout: col = lane&15, row = (lane>>4)*4 + reg
  const int orow = blockIdx.x * 64 + w * 16 + q * 4;
#pragma unroll
  for (int nt = 0; nt < 8; ++nt) {
    int col = nt * 16 + m;
#pragma unroll
    for (int rg = 0; rg < 4; ++rg) {
      int rr = orow + rg;
      if (rr < N) hA16[(size_t)rr * 128 + col] = f2bf(acc[nt][rg]);
    }
  }
}

// ---------- fused layer-1: CSR gather (bf16 hA) + self-loop + bias + relu + @W2 ----
// one wave per destination node; 1 dword (2 bf16) per lane per row
__global__ __launch_bounds__(256) void k_gather1(const int* __restrict__ ofs,
                                                 const int* __restrict__ cnt,
                                                 const int* __restrict__ bin,
                                                 const float* __restrict__ dinv,
                                                 const unsigned int* __restrict__ hA,
                                                 const float* __restrict__ b1,
                                                 const float* __restrict__ W2,
                                                 float* __restrict__ t2base, int N) {
  int d = blockIdx.x * 4 + (threadIdx.x >> 6);
  if (d >= N) return;
  const int lane = threadIdx.x & 63;
  const int beg = ofs[d], end = beg + cnt[d];
  float ax = 0.f, ay = 0.f;
  int e = beg;
  for (; e + 3 < end; e += 4) {
    int s0 = bin[e], s1 = bin[e + 1], s2 = bin[e + 2], s3 = bin[e + 3];
    float w0 = dinv[s0], w1 = dinv[s1], w2 = dinv[s2], w3 = dinv[s3];
    unsigned int v0 = hA[(size_t)s0 * 64 + lane];
    unsigned int v1 = hA[(size_t)s1 * 64 + lane];
    unsigned int v2 = hA[(size_t)s2 * 64 + lane];
    unsigned int v3 = hA[(size_t)s3 * 64 + lane];
    ax += w0 * bf2f(v0 & 0xffff) + w1 * bf2f(v1 & 0xffff) +
          w2 * bf2f(v2 & 0xffff) + w3 * bf2f(v3 & 0xffff);
    ay += w0 * bf2f(v0 >> 16) + w1 * bf2f(v1 >> 16) +
          w2 * bf2f(v2 >> 16) + w3 * bf2f(v3 >> 16);
  }
  for (; e < end; ++e) {
    int s = bin[e];
    float w = dinv[s];
    unsigned int v = hA[(size_t)s * 64 + lane];
    ax += w * bf2f(v & 0xffff);
    ay += w * bf2f(v >> 16);
  }
  const float dd = dinv[d];
  unsigned int vs = hA[(size_t)d * 64 + lane];
  float v0 = ax * dd + bf2f(vs & 0xffff) * dd * dd + b1[lane * 2];
  float v1 = ay * dd + bf2f(vs >> 16) * dd * dd + b1[lane * 2 + 1];
  v0 = fmaxf(v0, 0.f);
  v1 = fmaxf(v1, 0.f);
  float4 w2v = *(const float4*)&W2[lane * 4];
  float p0 = v0 * w2v.x + v1 * w2v.z;
  float p1 = v0 * w2v.y + v1 * w2v.w;
#pragma unroll
  for (int off = 32; off > 0; off >>= 1) {
    p0 += __shfl_down(p0, off);
    p1 += __shfl_down(p1, off);
  }
  if (lane == 0) *(float2*)&t2base[d * 2] = make_float2(p0, p1);
}

// ---------- fused final: layer-2 CSR gather + self-loop + b2 + x@W_skip + b_skip ----
__global__ __launch_bounds__(256) void k_final(const float* __restrict__ x,
                                               const float* __restrict__ W_skip,
                                               const float* __restrict__ b_skip,
                                               const float* __restrict__ b2,
                                               const float* __restrict__ t2base,
                                               const float* __restrict__ dinv,
                                               const int* __restrict__ ofs,
                                               const int* __restrict__ cnt,
                                               const int* __restrict__ bin,
                                               float* __restrict__ out, int N) {
  int i = blockIdx.x * 4 + (threadIdx.x >> 6);
  if (i >= N) return;
  const int lane = threadIdx.x & 63;
  float2 xv = *(const float2*)&x[(size_t)i * 128 + lane * 2];
  float4 wv = *(const float4*)&W_skip[lane * 4];
  float a0 = xv.x * wv.x + xv.y * wv.z;
  float a1 = xv.x * wv.y + xv.y * wv.w;
  const int beg = ofs[i], end = beg + cnt[i];
  float g0 = 0.f, g1 = 0.f;
  for (int e = beg + lane; e < end; e += 64) {
    int s = bin[e];
    float w = dinv[s];
    float2 t = *(const float2*)&t2base[s * 2];
    g0 += w * t.x; g1 += w * t.y;
  }
#pragma unroll
  for (int off = 32; off > 0; off >>= 1) {
    a0 += __shfl_down(a0, off);
    a1 += __shfl_down(a1, off);
    g0 += __shfl_down(g0, off);
    g1 += __shfl_down(g1, off);
  }
  if (lane == 0) {
    float di = dinv[i], d2 = di * di;
    float2 ts = *(const float2*)&t2base[i * 2];
    float o0 = g0 * di + ts.x * d2 + b2[0] + a0 + b_skip[0];
    float o1 = g1 * di + ts.y * d2 + b2[1] + a1 + b_skip[1];
    *(float2*)&out[i * 2] = make_float2(o0, o1);
  }
}

extern "C" void kernel_launch(void* const* d_in, const int* in_sizes, int n_in,
                              void* d_out, int out_size, void* d_ws, size_t ws_size,
                              hipStream_t stream) {
  const float* x      = (const float*)d_in[0];
  const int*   edges  = (const int*)d_in[1];
  const float* W1     = (const float*)d_in[2];
  const float* b1     = (const float*)d_in[3];
  const float* W2     = (const float*)d_in[4];
  const float* b2     = (const float*)d_in[5];
  const float* W_skip = (const float*)d_in[6];
  const float* b_skip = (const float*)d_in[7];
  float* out = (float*)d_out;

  const int N = NN;
  const int E = in_sizes[1] / 2;
  const int* src = edges;
  const int* dst = edges + E;

  // ws: [cnt N][cursor N][total 4][ofs N+4][dinv N][bin E][t2base 2N][Btg 8192][hA16 32N]
  int*   cnt    = (int*)d_ws;
  int*   cursor = cnt + N;
  int*   total  = cursor + N;
  int*   ofs    = total + 4;
  float* dinv   = (float*)(ofs + N + 4);
  int*   bin    = (int*)(dinv + N);
  float* t2base = (float*)(bin + E);
  unsigned short* Btg = (unsigned short*)(t2base + 2 * (size_t)N);
  unsigned short* hA16 = Btg + 16384;

  hipMemsetAsync(cnt, 0, (2 * (size_t)N + 4) * sizeof(int), stream);  // cnt+cursor+total

  k_wprep<<<64, 256, 0, stream>>>(W1, Btg);
  k_deg<<<(E + 255) / 256, 256, 0, stream>>>(dst, E, cnt);
  k_alloc<<<(N + 255) / 256, 256, 0, stream>>>(cnt, ofs, dinv, total, N);
  k_binfill<<<(E + 255) / 256, 256, 0, stream>>>(src, dst, E, ofs, cursor, bin);
  k_gemm1<<<(N + 63) / 64, 256, 0, stream>>>(x, Btg, hA16, N);
  k_gather1<<<(N + 3) / 4, 256, 0, stream>>>(ofs, cnt, bin, dinv,
                                             (const unsigned int*)hA16, b1, W2,
                                             t2base, N);
  k_final<<<(N + 3) / 4, 256, 0, stream>>>(x, W_skip, b_skip, b2, t2base, dinv, ofs,
                                           cnt, bin, out, N);
}